// Round 4
// baseline (306.757 us; speedup 1.0000x reference)
//
#include <hip/hip_runtime.h>

#define N_NODES 100000
#define N_EDGES 1200000
#define D 64

// ---------------- zero workspace (replaces pathological hipMemsetAsync) ----
__global__ __launch_bounds__(256) void zero_kernel(int4* __restrict__ p, int n4)
{
    int i = blockIdx.x * 256 + threadIdx.x;
    if (i < n4) p[i] = make_int4(0, 0, 0, 0);
}

// ---------------- CSR build ----------------
__global__ __launch_bounds__(256) void count_deg_kernel(
    const int* __restrict__ dst, int* __restrict__ deg)
{
    int e = blockIdx.x * 256 + threadIdx.x;
    if (e < N_EDGES) atomicAdd(&deg[dst[e]], 1);
}

__global__ __launch_bounds__(256) void scan_block_kernel(
    const int* __restrict__ deg, int* __restrict__ offs, int* __restrict__ blocksums)
{
    __shared__ int s[256];
    int tid = threadIdx.x;
    int base = blockIdx.x * 1024;
    int v[4]; int sum = 0;
    #pragma unroll
    for (int j = 0; j < 4; ++j) {
        int idx = base + tid * 4 + j;
        v[j] = (idx < N_NODES) ? deg[idx] : 0;
        sum += v[j];
    }
    s[tid] = sum; __syncthreads();
    for (int off = 1; off < 256; off <<= 1) {
        int t = (tid >= off) ? s[tid - off] : 0;
        __syncthreads();
        s[tid] += t;
        __syncthreads();
    }
    int run = s[tid] - sum;
    #pragma unroll
    for (int j = 0; j < 4; ++j) {
        int idx = base + tid * 4 + j;
        if (idx < N_NODES) offs[idx] = run;
        run += v[j];
    }
    if (tid == 255) blocksums[blockIdx.x] = s[255];
}

__global__ void scan_tops_kernel(int* __restrict__ blocksums, int nb)
{
    __shared__ int s[128];
    int tid = threadIdx.x;
    int v = (tid < nb) ? blocksums[tid] : 0;
    s[tid] = v; __syncthreads();
    for (int off = 1; off < 128; off <<= 1) {
        int t = (tid >= off) ? s[tid - off] : 0;
        __syncthreads();
        s[tid] += t;
        __syncthreads();
    }
    if (tid < nb) blocksums[tid] = s[tid] - v;
}

__global__ __launch_bounds__(256) void add_tops_kernel(
    int* __restrict__ offs, const int* __restrict__ blocksums)
{
    int i = blockIdx.x * 256 + threadIdx.x;
    if (i < N_NODES) offs[i] += blocksums[i >> 10];
}

__global__ __launch_bounds__(256) void scatter_edges_kernel(
    const int* __restrict__ src, const int* __restrict__ dst,
    const int* __restrict__ offs, int* __restrict__ cursor,
    int2* __restrict__ idx_s)
{
    int e = blockIdx.x * 256 + threadIdx.x;
    if (e >= N_EDGES) return;
    int d = dst[e];
    int pos = offs[d] + atomicAdd(&cursor[d], 1);
    idx_s[pos] = make_int2(e, src[e]);
}

// ---------------- weight prep: Wf = W_msg @ Wa_bot, c1 = b_msg @ Wa_bot ----
__global__ __launch_bounds__(64) void prep_w_kernel(
    const float* __restrict__ W_msg, const float* __restrict__ b_msg,
    const float* __restrict__ W_apply, float* __restrict__ Wf, float* __restrict__ c1)
{
    int j = threadIdx.x;
    int i = blockIdx.x;
    float acc = 0.f;
    if (i < 128) {
        for (int k = 0; k < 64; ++k)
            acc = fmaf(W_msg[i * 64 + k], W_apply[(64 + k) * 64 + j], acc);
        Wf[i * 64 + j] = acc;
    } else {
        for (int k = 0; k < 64; ++k)
            acc = fmaf(b_msg[k], W_apply[(64 + k) * 64 + j], acc);
        c1[j] = acc;
    }
}

// ---------------- gather: one wave per node, masked unroll-4 (no serial tail)
__global__ __launch_bounds__(256) void gather_kernel(
    const float* __restrict__ nfeats, const float* __restrict__ efeats,
    const int2* __restrict__ idx_s, const int* __restrict__ offs,
    const int* __restrict__ deg, float* __restrict__ agg_h, float* __restrict__ agg_e)
{
    int w = (int)((blockIdx.x * blockDim.x + threadIdx.x) >> 6);
    int lane = threadIdx.x & 63;
    if (w >= N_NODES) return;
    int beg = __builtin_amdgcn_readfirstlane(offs[w]);
    int dgi = __builtin_amdgcn_readfirstlane(deg[w]);
    float sh = 0.f, se = 0.f;
    int last = dgi - 1;
    for (int i = 0; i < dgi; i += 4) {
        int i1 = min(i + 1, last), i2 = min(i + 2, last), i3 = min(i + 3, last);
        float m1 = (i + 1 <= last) ? 1.f : 0.f;
        float m2 = (i + 2 <= last) ? 1.f : 0.f;
        float m3 = (i + 3 <= last) ? 1.f : 0.f;
        int2 p0 = idx_s[beg + i];
        int2 p1 = idx_s[beg + i1];
        int2 p2 = idx_s[beg + i2];
        int2 p3 = idx_s[beg + i3];
        float a0 = efeats[(size_t)p0.x * D + lane];
        float a1 = efeats[(size_t)p1.x * D + lane];
        float a2 = efeats[(size_t)p2.x * D + lane];
        float a3 = efeats[(size_t)p3.x * D + lane];
        float b0 = nfeats[(size_t)p0.y * D + lane];
        float b1 = nfeats[(size_t)p1.y * D + lane];
        float b2 = nfeats[(size_t)p2.y * D + lane];
        float b3 = nfeats[(size_t)p3.y * D + lane];
        se += a0; se = fmaf(m1, a1, se); se = fmaf(m2, a2, se); se = fmaf(m3, a3, se);
        sh += b0; sh = fmaf(m1, b1, sh); sh = fmaf(m2, b2, sh); sh = fmaf(m3, b3, sh);
    }
    agg_h[(size_t)w * D + lane] = sh;
    agg_e[(size_t)w * D + lane] = se;
}

// ---------------- node update: lane = node, weights via scalar regs ---------
__global__ __launch_bounds__(64) void node_update_kernel(
    const float* __restrict__ nfeats, const float* __restrict__ W_apply,
    const float* __restrict__ b_apply, const float* __restrict__ Wf,
    const float* __restrict__ c1, const float* __restrict__ agg_e,
    const int* __restrict__ deg, float* __restrict__ out /* holds agg_h */)
{
    __shared__ float sT[64 * 65];
    int lane = threadIdx.x;
    int node0 = blockIdx.x * 64 + lane;
    int node = node0 < N_NODES ? node0 : N_NODES - 1;
    int dgi = deg[node];
    float s = dgi > 0 ? 1.f / (float)dgi : 0.f;
    float gate = dgi > 0 ? 1.f : 0.f;

    float acc[64];
    #pragma unroll
    for (int j = 0; j < 64; ++j) acc[j] = 0.f;

    const float* nfr = nfeats + (size_t)node * D;
    const float* shr = out + (size_t)node * D;      // agg_h
    const float* ser = agg_e + (size_t)node * D;

    for (int k4 = 0; k4 < 64; k4 += 4) {
        float4 x = *(const float4*)(nfr + k4);
        #pragma unroll
        for (int kk = 0; kk < 4; ++kk) {
            float xv = (&x.x)[kk];
            const float* wr = W_apply + (size_t)(k4 + kk) * 64;
            #pragma unroll
            for (int j = 0; j < 64; ++j) acc[j] = fmaf(xv, wr[j], acc[j]);
        }
    }
    for (int k4 = 0; k4 < 64; k4 += 4) {
        float4 x = *(const float4*)(shr + k4);
        #pragma unroll
        for (int kk = 0; kk < 4; ++kk) {
            float xv = (&x.x)[kk] * s;
            const float* wr = Wf + (size_t)(k4 + kk) * 64;
            #pragma unroll
            for (int j = 0; j < 64; ++j) acc[j] = fmaf(xv, wr[j], acc[j]);
        }
    }
    for (int k4 = 0; k4 < 64; k4 += 4) {
        float4 x = *(const float4*)(ser + k4);
        #pragma unroll
        for (int kk = 0; kk < 4; ++kk) {
            float xv = (&x.x)[kk] * s;
            const float* wr = Wf + (size_t)(64 + k4 + kk) * 64;
            #pragma unroll
            for (int j = 0; j < 64; ++j) acc[j] = fmaf(xv, wr[j], acc[j]);
        }
    }

    #pragma unroll
    for (int j = 0; j < 64; ++j)
        sT[lane * 65 + j] = fmaxf(acc[j] + gate * c1[j] + b_apply[j], 0.f);
    __syncthreads();

    int nbase = blockIdx.x * 64;
    for (int n = 0; n < 64; ++n) {
        int nd = nbase + n;
        if (nd >= N_NODES) break;
        out[(size_t)nd * D + lane] = sT[n * 65 + lane];
    }
}

extern "C" void kernel_launch(void* const* d_in, const int* in_sizes, int n_in,
                              void* d_out, int out_size, void* d_ws, size_t ws_size,
                              hipStream_t stream) {
    const float* nfeats  = (const float*)d_in[0];
    const float* efeats  = (const float*)d_in[1];
    const int*   src     = (const int*)d_in[2];
    const int*   dst     = (const int*)d_in[3];
    const float* W_msg   = (const float*)d_in[4];
    const float* b_msg   = (const float*)d_in[5];
    const float* W_apply = (const float*)d_in[6];
    const float* b_apply = (const float*)d_in[7];
    float* out = (float*)d_out;

    // ws layout: [deg | cursor | offs | blocksums(128) | Wf(8192f) | c1(64f) | idx int2(E) | agg_e(N*64 f)]
    int* deg       = (int*)d_ws;
    int* cursor    = deg + N_NODES;
    int* offs      = cursor + N_NODES;
    int* blocksums = offs + N_NODES;
    float* Wf      = (float*)(blocksums + 128);
    float* c1      = Wf + 128 * 64;
    int2* idx_s    = (int2*)(c1 + 64);
    float* agg_e   = (float*)(idx_s + N_EDGES);

    // zero deg + cursor (800 KB) with our own kernel
    int n4 = (2 * N_NODES) / 4;   // 50000 int4
    zero_kernel<<<(n4 + 255) / 256, 256, 0, stream>>>((int4*)d_ws, n4);

    prep_w_kernel<<<129, 64, 0, stream>>>(W_msg, b_msg, W_apply, Wf, c1);

    int eb = (N_EDGES + 255) / 256;
    count_deg_kernel<<<eb, 256, 0, stream>>>(dst, deg);

    int nscan = (N_NODES + 1023) / 1024;   // 98
    scan_block_kernel<<<nscan, 256, 0, stream>>>(deg, offs, blocksums);
    scan_tops_kernel<<<1, 128, 0, stream>>>(blocksums, nscan);
    add_tops_kernel<<<(N_NODES + 255) / 256, 256, 0, stream>>>(offs, blocksums);

    scatter_edges_kernel<<<eb, 256, 0, stream>>>(src, dst, offs, cursor, idx_s);

    gather_kernel<<<N_NODES / 4, 256, 0, stream>>>(
        nfeats, efeats, idx_s, offs, deg, out /*agg_h*/, agg_e);

    node_update_kernel<<<(N_NODES + 63) / 64, 64, 0, stream>>>(
        nfeats, W_apply, b_apply, Wf, c1, agg_e, deg, out);
}

// Round 6
// 301.821 us; speedup vs baseline: 1.0164x; 1.0164x over previous
//
#include <hip/hip_runtime.h>

#define N_NODES 100000
#define N_EDGES 1200000
#define D 64

typedef float f32x4 __attribute__((ext_vector_type(4)));

// ---------------- zero workspace ----------------
__global__ __launch_bounds__(256) void zero_kernel(int4* __restrict__ p, int n4)
{
    int i = blockIdx.x * 256 + threadIdx.x;
    if (i < n4) p[i] = make_int4(0, 0, 0, 0);
}

// ---------------- CSR build ----------------
__global__ __launch_bounds__(256) void count_deg_kernel(
    const int* __restrict__ dst, int* __restrict__ deg)
{
    int e = blockIdx.x * 256 + threadIdx.x;
    if (e < N_EDGES) atomicAdd(&deg[dst[e]], 1);
}

__global__ __launch_bounds__(256) void scan_block_kernel(
    const int* __restrict__ deg, int* __restrict__ offs, int* __restrict__ blocksums)
{
    __shared__ int s[256];
    int tid = threadIdx.x;
    int base = blockIdx.x * 1024;
    int v[4]; int sum = 0;
    #pragma unroll
    for (int j = 0; j < 4; ++j) {
        int idx = base + tid * 4 + j;
        v[j] = (idx < N_NODES) ? deg[idx] : 0;
        sum += v[j];
    }
    s[tid] = sum; __syncthreads();
    for (int off = 1; off < 256; off <<= 1) {
        int t = (tid >= off) ? s[tid - off] : 0;
        __syncthreads();
        s[tid] += t;
        __syncthreads();
    }
    int run = s[tid] - sum;
    #pragma unroll
    for (int j = 0; j < 4; ++j) {
        int idx = base + tid * 4 + j;
        if (idx < N_NODES) offs[idx] = run;
        run += v[j];
    }
    if (tid == 255) blocksums[blockIdx.x] = s[255];
}

__global__ void scan_tops_kernel(int* __restrict__ blocksums, int nb)
{
    __shared__ int s[128];
    int tid = threadIdx.x;
    int v = (tid < nb) ? blocksums[tid] : 0;
    s[tid] = v; __syncthreads();
    for (int off = 1; off < 128; off <<= 1) {
        int t = (tid >= off) ? s[tid - off] : 0;
        __syncthreads();
        s[tid] += t;
        __syncthreads();
    }
    if (tid < nb) blocksums[tid] = s[tid] - v;
}

__global__ __launch_bounds__(256) void add_tops_kernel(
    int* __restrict__ offs, const int* __restrict__ blocksums)
{
    int i = blockIdx.x * 256 + threadIdx.x;
    if (i < N_NODES) offs[i] += blocksums[i >> 10];
}

__global__ __launch_bounds__(256) void scatter_edges_kernel(
    const int* __restrict__ src, const int* __restrict__ dst,
    const int* __restrict__ offs, int* __restrict__ cursor,
    int2* __restrict__ idx_s)
{
    int e = blockIdx.x * 256 + threadIdx.x;
    if (e >= N_EDGES) return;
    int d = dst[e];
    int pos = offs[d] + atomicAdd(&cursor[d], 1);
    idx_s[pos] = make_int2(e, src[e]);
}

// ---------------- weight prep: Wf = W_msg @ Wa_bot, c1 = b_msg @ Wa_bot ----
__global__ __launch_bounds__(64) void prep_w_kernel(
    const float* __restrict__ W_msg, const float* __restrict__ b_msg,
    const float* __restrict__ W_apply, float* __restrict__ Wf, float* __restrict__ c1)
{
    int j = threadIdx.x;
    int i = blockIdx.x;
    float acc = 0.f;
    if (i < 128) {
        for (int k = 0; k < 64; ++k)
            acc = fmaf(W_msg[i * 64 + k], W_apply[(64 + k) * 64 + j], acc);
        Wf[i * 64 + j] = acc;
    } else {
        for (int k = 0; k < 64; ++k)
            acc = fmaf(b_msg[k], W_apply[(64 + k) * 64 + j], acc);
        c1[j] = acc;
    }
}

// ---------------- gather v2: lane=(edge-slot r, col-quad c4), float4 loads --
// One wave per node; 4 edge rows in flight per load instruction, 8 edges per
// iteration. Cross-slot reduce via shfl_xor(16/32) at the end.
__global__ __launch_bounds__(256) void gather_kernel(
    const float* __restrict__ nfeats, const float* __restrict__ efeats,
    const int2* __restrict__ idx_s, const int* __restrict__ offs,
    const int* __restrict__ deg, float* __restrict__ agg_h, float* __restrict__ agg_e)
{
    int w = (int)((blockIdx.x * blockDim.x + threadIdx.x) >> 6);
    int lane = threadIdx.x & 63;
    if (w >= N_NODES) return;
    int r  = lane >> 4;          // edge slot 0..3
    int c4 = (lane & 15) << 2;   // column start 0,4,..,60
    int beg = __builtin_amdgcn_readfirstlane(offs[w]);
    int dgi = __builtin_amdgcn_readfirstlane(deg[w]);
    f32x4 sh = (f32x4)0.f;
    f32x4 se = (f32x4)0.f;
    int last = dgi - 1;
    for (int i = 0; i < dgi; i += 8) {
        int iA = i + r, iB = i + 4 + r;
        int2 pA = idx_s[beg + min(iA, last)];
        int2 pB = idx_s[beg + min(iB, last)];
        float mA = (iA <= last) ? 1.f : 0.f;
        float mB = (iB <= last) ? 1.f : 0.f;
        f32x4 eA = __builtin_nontemporal_load(
            (const f32x4*)(efeats + (size_t)pA.x * D + c4));
        f32x4 eB = __builtin_nontemporal_load(
            (const f32x4*)(efeats + (size_t)pB.x * D + c4));
        f32x4 hA = *(const f32x4*)(nfeats + (size_t)pA.y * D + c4);
        f32x4 hB = *(const f32x4*)(nfeats + (size_t)pB.y * D + c4);
        #pragma unroll
        for (int q = 0; q < 4; ++q) {
            se[q] = fmaf(mA, eA[q], se[q]);
            sh[q] = fmaf(mA, hA[q], sh[q]);
            se[q] = fmaf(mB, eB[q], se[q]);
            sh[q] = fmaf(mB, hB[q], sh[q]);
        }
    }
    // reduce across the 4 edge slots (lanes r differ by bits 4,5)
    #pragma unroll
    for (int m = 16; m <= 32; m <<= 1) {
        #pragma unroll
        for (int q = 0; q < 4; ++q) {
            sh[q] += __shfl_xor(sh[q], m);
            se[q] += __shfl_xor(se[q], m);
        }
    }
    if (r == 0)       *(f32x4*)(agg_h + (size_t)w * D + c4) = sh;
    else if (r == 1)  *(f32x4*)(agg_e + (size_t)w * D + c4) = se;
}

// ---------------- node update: lane = node, weights via uniform loads -------
__global__ __launch_bounds__(64) void node_update_kernel(
    const float* __restrict__ nfeats, const float* __restrict__ W_apply,
    const float* __restrict__ b_apply, const float* __restrict__ Wf,
    const float* __restrict__ c1, const float* __restrict__ agg_e,
    const int* __restrict__ deg, float* __restrict__ out /* holds agg_h */)
{
    __shared__ float sT[64 * 65];
    int lane = threadIdx.x;
    int node0 = blockIdx.x * 64 + lane;
    int node = node0 < N_NODES ? node0 : N_NODES - 1;
    int dgi = deg[node];
    float s = dgi > 0 ? 1.f / (float)dgi : 0.f;
    float gate = dgi > 0 ? 1.f : 0.f;

    float acc[64];
    #pragma unroll
    for (int j = 0; j < 64; ++j) acc[j] = 0.f;

    const float* nfr = nfeats + (size_t)node * D;
    const float* shr = out + (size_t)node * D;      // agg_h
    const float* ser = agg_e + (size_t)node * D;

    for (int k4 = 0; k4 < 64; k4 += 4) {
        float4 x = *(const float4*)(nfr + k4);
        #pragma unroll
        for (int kk = 0; kk < 4; ++kk) {
            float xv = (&x.x)[kk];
            const float* wr = W_apply + (size_t)(k4 + kk) * 64;
            #pragma unroll
            for (int j = 0; j < 64; ++j) acc[j] = fmaf(xv, wr[j], acc[j]);
        }
    }
    for (int k4 = 0; k4 < 64; k4 += 4) {
        float4 x = *(const float4*)(shr + k4);
        #pragma unroll
        for (int kk = 0; kk < 4; ++kk) {
            float xv = (&x.x)[kk] * s;
            const float* wr = Wf + (size_t)(k4 + kk) * 64;
            #pragma unroll
            for (int j = 0; j < 64; ++j) acc[j] = fmaf(xv, wr[j], acc[j]);
        }
    }
    for (int k4 = 0; k4 < 64; k4 += 4) {
        float4 x = *(const float4*)(ser + k4);
        #pragma unroll
        for (int kk = 0; kk < 4; ++kk) {
            float xv = (&x.x)[kk] * s;
            const float* wr = Wf + (size_t)(64 + k4 + kk) * 64;
            #pragma unroll
            for (int j = 0; j < 64; ++j) acc[j] = fmaf(xv, wr[j], acc[j]);
        }
    }

    #pragma unroll
    for (int j = 0; j < 64; ++j)
        sT[lane * 65 + j] = fmaxf(acc[j] + gate * c1[j] + b_apply[j], 0.f);
    __syncthreads();

    int nbase = blockIdx.x * 64;
    for (int n = 0; n < 64; ++n) {
        int nd = nbase + n;
        if (nd >= N_NODES) break;
        out[(size_t)nd * D + lane] = sT[n * 65 + lane];
    }
}

extern "C" void kernel_launch(void* const* d_in, const int* in_sizes, int n_in,
                              void* d_out, int out_size, void* d_ws, size_t ws_size,
                              hipStream_t stream) {
    const float* nfeats  = (const float*)d_in[0];
    const float* efeats  = (const float*)d_in[1];
    const int*   src     = (const int*)d_in[2];
    const int*   dst     = (const int*)d_in[3];
    const float* W_msg   = (const float*)d_in[4];
    const float* b_msg   = (const float*)d_in[5];
    const float* W_apply = (const float*)d_in[6];
    const float* b_apply = (const float*)d_in[7];
    float* out = (float*)d_out;

    // ws layout: [deg | cursor | offs | blocksums(128) | Wf(8192f) | c1(64f) | idx int2(E) | agg_e(N*64 f)]
    int* deg       = (int*)d_ws;
    int* cursor    = deg + N_NODES;
    int* offs      = cursor + N_NODES;
    int* blocksums = offs + N_NODES;
    float* Wf      = (float*)(blocksums + 128);
    float* c1      = Wf + 128 * 64;
    int2* idx_s    = (int2*)(c1 + 64);
    float* agg_e   = (float*)(idx_s + N_EDGES);

    int n4 = (2 * N_NODES) / 4;   // deg + cursor
    zero_kernel<<<(n4 + 255) / 256, 256, 0, stream>>>((int4*)d_ws, n4);

    prep_w_kernel<<<129, 64, 0, stream>>>(W_msg, b_msg, W_apply, Wf, c1);

    int eb = (N_EDGES + 255) / 256;
    count_deg_kernel<<<eb, 256, 0, stream>>>(dst, deg);

    int nscan = (N_NODES + 1023) / 1024;   // 98
    scan_block_kernel<<<nscan, 256, 0, stream>>>(deg, offs, blocksums);
    scan_tops_kernel<<<1, 128, 0, stream>>>(blocksums, nscan);
    add_tops_kernel<<<(N_NODES + 255) / 256, 256, 0, stream>>>(offs, blocksums);

    scatter_edges_kernel<<<eb, 256, 0, stream>>>(src, dst, offs, cursor, idx_s);

    gather_kernel<<<N_NODES / 4, 256, 0, stream>>>(
        nfeats, efeats, idx_s, offs, deg, out /*agg_h*/, agg_e);

    node_update_kernel<<<(N_NODES + 63) / 64, 64, 0, stream>>>(
        nfeats, W_apply, b_apply, Wf, c1, agg_e, deg, out);
}

// Round 7
// 293.647 us; speedup vs baseline: 1.0446x; 1.0278x over previous
//
#include <hip/hip_runtime.h>

#define N_NODES 100000
#define N_EDGES 1200000
#define D 64

typedef float f32x4 __attribute__((ext_vector_type(4)));

// ---------------- zero workspace ----------------
__global__ __launch_bounds__(256) void zero_kernel(int4* __restrict__ p, int n4)
{
    int i = blockIdx.x * 256 + threadIdx.x;
    if (i < n4) p[i] = make_int4(0, 0, 0, 0);
}

// ---------------- CSR build ----------------
__global__ __launch_bounds__(256) void count_deg_kernel(
    const int* __restrict__ dst, int* __restrict__ deg)
{
    int e = blockIdx.x * 256 + threadIdx.x;
    if (e < N_EDGES) atomicAdd(&deg[dst[e]], 1);
}

__global__ __launch_bounds__(256) void scan_block_kernel(
    const int* __restrict__ deg, int* __restrict__ offs, int* __restrict__ blocksums)
{
    __shared__ int s[256];
    int tid = threadIdx.x;
    int base = blockIdx.x * 1024;
    int v[4]; int sum = 0;
    #pragma unroll
    for (int j = 0; j < 4; ++j) {
        int idx = base + tid * 4 + j;
        v[j] = (idx < N_NODES) ? deg[idx] : 0;
        sum += v[j];
    }
    s[tid] = sum; __syncthreads();
    for (int off = 1; off < 256; off <<= 1) {
        int t = (tid >= off) ? s[tid - off] : 0;
        __syncthreads();
        s[tid] += t;
        __syncthreads();
    }
    int run = s[tid] - sum;
    #pragma unroll
    for (int j = 0; j < 4; ++j) {
        int idx = base + tid * 4 + j;
        if (idx < N_NODES) offs[idx] = run;
        run += v[j];
    }
    if (tid == 255) blocksums[blockIdx.x] = s[255];
}

__global__ void scan_tops_kernel(int* __restrict__ blocksums, int nb)
{
    __shared__ int s[128];
    int tid = threadIdx.x;
    int v = (tid < nb) ? blocksums[tid] : 0;
    s[tid] = v; __syncthreads();
    for (int off = 1; off < 128; off <<= 1) {
        int t = (tid >= off) ? s[tid - off] : 0;
        __syncthreads();
        s[tid] += t;
        __syncthreads();
    }
    if (tid < nb) blocksums[tid] = s[tid] - v;
}

__global__ __launch_bounds__(256) void add_tops_kernel(
    int* __restrict__ offs, const int* __restrict__ blocksums)
{
    int i = blockIdx.x * 256 + threadIdx.x;
    if (i < N_NODES) offs[i] += blocksums[i >> 10];
}

__global__ __launch_bounds__(256) void scatter_edges_kernel(
    const int* __restrict__ src, const int* __restrict__ dst,
    const int* __restrict__ offs, int* __restrict__ cursor,
    int2* __restrict__ idx_s)
{
    int e = blockIdx.x * 256 + threadIdx.x;
    if (e >= N_EDGES) return;
    int d = dst[e];
    int pos = offs[d] + atomicAdd(&cursor[d], 1);
    idx_s[pos] = make_int2(e, src[e]);
}

// ---------------- weight prep: Wf = W_msg @ Wa_bot, c1 = b_msg @ Wa_bot ----
__global__ __launch_bounds__(64) void prep_w_kernel(
    const float* __restrict__ W_msg, const float* __restrict__ b_msg,
    const float* __restrict__ W_apply, float* __restrict__ Wf, float* __restrict__ c1)
{
    int j = threadIdx.x;
    int i = blockIdx.x;
    float acc = 0.f;
    if (i < 128) {
        for (int k = 0; k < 64; ++k)
            acc = fmaf(W_msg[i * 64 + k], W_apply[(64 + k) * 64 + j], acc);
        Wf[i * 64 + j] = acc;
    } else {
        for (int k = 0; k < 64; ++k)
            acc = fmaf(b_msg[k], W_apply[(64 + k) * 64 + j], acc);
        c1[j] = acc;
    }
}

// ---------------- gather v2 (unchanged from R6) ----------------
__global__ __launch_bounds__(256) void gather_kernel(
    const float* __restrict__ nfeats, const float* __restrict__ efeats,
    const int2* __restrict__ idx_s, const int* __restrict__ offs,
    const int* __restrict__ deg, float* __restrict__ agg_h, float* __restrict__ agg_e)
{
    int w = (int)((blockIdx.x * blockDim.x + threadIdx.x) >> 6);
    int lane = threadIdx.x & 63;
    if (w >= N_NODES) return;
    int r  = lane >> 4;          // edge slot 0..3
    int c4 = (lane & 15) << 2;   // column start 0,4,..,60
    int beg = __builtin_amdgcn_readfirstlane(offs[w]);
    int dgi = __builtin_amdgcn_readfirstlane(deg[w]);
    f32x4 sh = (f32x4)0.f;
    f32x4 se = (f32x4)0.f;
    int last = dgi - 1;
    for (int i = 0; i < dgi; i += 8) {
        int iA = i + r, iB = i + 4 + r;
        int2 pA = idx_s[beg + min(iA, last)];
        int2 pB = idx_s[beg + min(iB, last)];
        float mA = (iA <= last) ? 1.f : 0.f;
        float mB = (iB <= last) ? 1.f : 0.f;
        f32x4 eA = __builtin_nontemporal_load(
            (const f32x4*)(efeats + (size_t)pA.x * D + c4));
        f32x4 eB = __builtin_nontemporal_load(
            (const f32x4*)(efeats + (size_t)pB.x * D + c4));
        f32x4 hA = *(const f32x4*)(nfeats + (size_t)pA.y * D + c4);
        f32x4 hB = *(const f32x4*)(nfeats + (size_t)pB.y * D + c4);
        #pragma unroll
        for (int q = 0; q < 4; ++q) {
            se[q] = fmaf(mA, eA[q], se[q]);
            sh[q] = fmaf(mA, hA[q], sh[q]);
            se[q] = fmaf(mB, eB[q], se[q]);
            sh[q] = fmaf(mB, hB[q], sh[q]);
        }
    }
    #pragma unroll
    for (int m = 16; m <= 32; m <<= 1) {
        #pragma unroll
        for (int q = 0; q < 4; ++q) {
            sh[q] += __shfl_xor(sh[q], m);
            se[q] += __shfl_xor(se[q], m);
        }
    }
    if (r == 0)       *(f32x4*)(agg_h + (size_t)w * D + c4) = sh;
    else if (r == 1)  *(f32x4*)(agg_e + (size_t)w * D + c4) = se;
}

// ---------------- node update v2: LDS-staged coalesced tall-skinny GEMM ----
// 64 threads = 1 wave per block, 64 nodes per block. k-panels of 16 staged
// into LDS with coalesced float4 loads; two accumulators (nf part / Wf part).
__global__ __launch_bounds__(64) void node_update_kernel(
    const float* __restrict__ nfeats, const float* __restrict__ W_apply,
    const float* __restrict__ b_apply, const float* __restrict__ Wf,
    const float* __restrict__ c1, const float* __restrict__ agg_e,
    const int* __restrict__ deg, float* out /* holds agg_h; no restrict */)
{
    __shared__ float sX[64 * 17];      // 64 rows x 16 k, stride 17 (2-way banks)
    __shared__ float sOut[64 * 65];    // transpose buffer, stride 65 (conflict-free)
    int t = threadIdx.x;
    int node0 = blockIdx.x * 64;
    int node = min(node0 + t, N_NODES - 1);
    int dgi = deg[node];
    float s = dgi > 0 ? 1.f / (float)dgi : 0.f;
    float gate = dgi > 0 ? 1.f : 0.f;

    float accN[64], accX[64];
    #pragma unroll
    for (int j = 0; j < 64; ++j) { accN[j] = 0.f; accX[j] = 0.f; }

    // stage one 64-row x 16-col panel of src (cols [kp,kp+16)) into sX
    #define STAGE(srcp, kp)                                                   \
    {                                                                         \
        _Pragma("unroll")                                                     \
        for (int e = 0; e < 4; ++e) {                                         \
            int flat = e * 64 + t;                                            \
            int row = flat >> 2, kq = flat & 3;                               \
            int grow = min(node0 + row, N_NODES - 1);                         \
            f32x4 v = *(const f32x4*)((srcp) + (size_t)grow * D + (kp) + kq * 4); \
            sX[row * 17 + kq * 4 + 0] = v[0];                                 \
            sX[row * 17 + kq * 4 + 1] = v[1];                                 \
            sX[row * 17 + kq * 4 + 2] = v[2];                                 \
            sX[row * 17 + kq * 4 + 3] = v[3];                                 \
        }                                                                     \
    }

    // accumulate panel: acc[j] += sX[t][kk] * W[(kw0+kk)*64 + j]
    #define ACCUM(acc, Wp, kw0)                                               \
    {                                                                         \
        _Pragma("unroll")                                                     \
        for (int g = 0; g < 4; ++g) {                                         \
            float x0 = sX[t * 17 + g * 4 + 0];                                \
            float x1 = sX[t * 17 + g * 4 + 1];                                \
            float x2 = sX[t * 17 + g * 4 + 2];                                \
            float x3 = sX[t * 17 + g * 4 + 3];                                \
            const float* w0 = (Wp) + (size_t)((kw0) + g * 4 + 0) * 64;        \
            const float* w1 = (Wp) + (size_t)((kw0) + g * 4 + 1) * 64;        \
            const float* w2 = (Wp) + (size_t)((kw0) + g * 4 + 2) * 64;        \
            const float* w3 = (Wp) + (size_t)((kw0) + g * 4 + 3) * 64;        \
            _Pragma("unroll")                                                 \
            for (int j = 0; j < 64; ++j) {                                    \
                acc[j] = fmaf(x0, w0[j], acc[j]);                             \
                acc[j] = fmaf(x1, w1[j], acc[j]);                             \
                acc[j] = fmaf(x2, w2[j], acc[j]);                             \
                acc[j] = fmaf(x3, w3[j], acc[j]);                             \
            }                                                                 \
        }                                                                     \
    }

    // nfeats @ Wa_top : k = 0..63
    for (int p = 0; p < 4; ++p) {
        STAGE(nfeats, p * 16);
        __syncthreads();
        ACCUM(accN, W_apply, p * 16);
        __syncthreads();
    }
    // [sh | se] @ Wf : k = 0..127 (sh rows live in `out`)
    for (int p = 0; p < 8; ++p) {
        const float* srcp = (p < 4) ? out : agg_e;
        STAGE(srcp, (p & 3) * 16);
        __syncthreads();
        ACCUM(accX, Wf, p * 16);
        __syncthreads();
    }

    #pragma unroll
    for (int j = 0; j < 64; ++j)
        sOut[t * 65 + j] = fmaxf(accN[j] + s * accX[j] + gate * c1[j] + b_apply[j], 0.f);
    __syncthreads();

    for (int n = 0; n < 64; ++n) {
        int nd = node0 + n;
        if (nd >= N_NODES) break;
        out[(size_t)nd * D + t] = sOut[n * 65 + t];
    }
    #undef STAGE
    #undef ACCUM
}

extern "C" void kernel_launch(void* const* d_in, const int* in_sizes, int n_in,
                              void* d_out, int out_size, void* d_ws, size_t ws_size,
                              hipStream_t stream) {
    const float* nfeats  = (const float*)d_in[0];
    const float* efeats  = (const float*)d_in[1];
    const int*   src     = (const int*)d_in[2];
    const int*   dst     = (const int*)d_in[3];
    const float* W_msg   = (const float*)d_in[4];
    const float* b_msg   = (const float*)d_in[5];
    const float* W_apply = (const float*)d_in[6];
    const float* b_apply = (const float*)d_in[7];
    float* out = (float*)d_out;

    // ws layout: [deg | cursor | offs | blocksums(128) | Wf(8192f) | c1(64f) | idx int2(E) | agg_e(N*64 f)]
    int* deg       = (int*)d_ws;
    int* cursor    = deg + N_NODES;
    int* offs      = cursor + N_NODES;
    int* blocksums = offs + N_NODES;
    float* Wf      = (float*)(blocksums + 128);
    float* c1      = Wf + 128 * 64;
    int2* idx_s    = (int2*)(c1 + 64);
    float* agg_e   = (float*)(idx_s + N_EDGES);

    int n4 = (2 * N_NODES) / 4;   // deg + cursor
    zero_kernel<<<(n4 + 255) / 256, 256, 0, stream>>>((int4*)d_ws, n4);

    prep_w_kernel<<<129, 64, 0, stream>>>(W_msg, b_msg, W_apply, Wf, c1);

    int eb = (N_EDGES + 255) / 256;
    count_deg_kernel<<<eb, 256, 0, stream>>>(dst, deg);

    int nscan = (N_NODES + 1023) / 1024;   // 98
    scan_block_kernel<<<nscan, 256, 0, stream>>>(deg, offs, blocksums);
    scan_tops_kernel<<<1, 128, 0, stream>>>(blocksums, nscan);
    add_tops_kernel<<<(N_NODES + 255) / 256, 256, 0, stream>>>(offs, blocksums);

    scatter_edges_kernel<<<eb, 256, 0, stream>>>(src, dst, offs, cursor, idx_s);

    gather_kernel<<<N_NODES / 4, 256, 0, stream>>>(
        nfeats, efeats, idx_s, offs, deg, out /*agg_h*/, agg_e);

    node_update_kernel<<<(N_NODES + 63) / 64, 64, 0, stream>>>(
        nfeats, W_apply, b_apply, Wf, c1, agg_e, deg, out);
}